// Round 11
// baseline (728.336 us; speedup 1.0000x reference)
//
#include <hip/hip_runtime.h>

static constexpr int B_ = 8;
static constexpr int N_ = 16384;
static constexpr int D_ = 256;
static constexpr int L_ = 64;

static constexpr int TPB = 512;       // 256 WGs x 512 thr, 1 WG/CU (LDS-forced), 1 point/thread
static constexpr int LF4 = 18;        // dims 0..71 in LDS
static constexpr int RF4 = 64 - LF4;  // dims 72..255 in VGPRs (46 float4)

// ws layout (init zeroes 139264 B every call; ws poisoned 0xAA once):
//   slot u64[8][64][32] @ 0       (131072 B)  packed (dist_bits<<32)|(~n) per WG per step
//   gadj u32[8][128]    @ 131072  (  4096 B)  64x64 edge bitmask per batch
//   cnt  u32[8]         @ 135168  (    32 B)  finalize arrival counters

__global__ void __launch_bounds__(1024)
init_kernel(unsigned int* __restrict__ z)
{
    z[blockIdx.x * 1024 + threadIdx.x] = 0u;   // grid 34 -> 139264 B
}

// ---------------------------------------------------------------------------
// Fused FPS scan + witness + finalize. Single-phase, single-store barrier:
//   per step each WG publishes ONE relaxed u64 key (dist>0 -> key!=0, so the
//   zero-init is the not-ready sentinel); every WG's wave 0 polls all 32
//   slots and max-reduces redundantly (identical winner everywhere).
// Landmark norm is recomputed locally from the scalar-loaded row every step
// (r6-validated op order -> bit-identical), so no payload/ordering is needed.
// All FMA/compare orders bit-identical to the r5..r10-validated kernels.
// ---------------------------------------------------------------------------
__global__ __attribute__((amdgpu_flat_work_group_size(512, 512),
                          amdgpu_waves_per_eu(2, 2)))
void fps_all_kernel(const float* __restrict__ emb, const float* __restrict__ csp,
                    unsigned long long* __restrict__ slot,
                    unsigned int* __restrict__ gadj,
                    unsigned int* __restrict__ cnt,
                    float* __restrict__ out)
{
    const int wg  = blockIdx.x;        // 0..255
    const int b   = wg >> 5;           // batch (32 WGs/batch)
    const int wib = wg & 31;
    const int tid = threadIdx.x;
    const int n   = (wib << 9) + tid;  // my point
    const float c = fabsf(csp[0]);

    __shared__ float4 slab[LF4 * TPB];          // 147456 B resident slice
    __shared__ float wval[8];
    __shared__ int   widx[8];
    __shared__ int   s_next;
    __shared__ int   s_lead;
    __shared__ unsigned int lmask[128];
    __shared__ int   labels[64];

    if (tid < 128) lmask[tid] = 0u;

    const float4* __restrict__ pt = (const float4*)(emb + (size_t)(b * N_ + n) * D_);

    // resident load + norm (sequential 4-acc over k=0..63, matches r1..r10)
    float4 p[RF4];
    float s0 = 0.f, s1 = 0.f, s2 = 0.f, s3 = 0.f;
    #pragma unroll
    for (int k = 0; k < LF4; ++k) {
        float4 v = pt[k];
        slab[k * TPB + tid] = v;
        s0 = fmaf(v.x, v.x, s0); s1 = fmaf(v.y, v.y, s1);
        s2 = fmaf(v.z, v.z, s2); s3 = fmaf(v.w, v.w, s3);
    }
    #pragma unroll
    for (int k = 0; k < RF4; ++k) {
        float4 v = pt[LF4 + k];
        p[k] = v;
        s0 = fmaf(v.x, v.x, s0); s1 = fmaf(v.y, v.y, s1);
        s2 = fmaf(v.z, v.z, s2); s3 = fmaf(v.w, v.w, s3);
    }
    const float my_xn = (s0 + s1) + (s2 + s3);

    float min_d = __builtin_inff();
    float b1v = __builtin_inff(), b2v = __builtin_inff();
    int   b1i = 0, b2i = 0;
    int   lm  = 0;      // landmark 0 = point 0

    #pragma unroll 1
    for (int s = 1; s <= L_; ++s) {
        // uniform (SGPR) pointer to landmark row s-1 — scalar-load path (r10)
        const int lmU = __builtin_amdgcn_readfirstlane(lm);
        const float4* __restrict__ w4 =
            (const float4*)(emb + (size_t)(b * N_ + lmU) * D_);

        // landmark norm recomputed locally every step (r6-validated op order);
        // overlaps the distance FMA stream below (both consume w4).
        float t0 = 0.f, t1 = 0.f, t2 = 0.f, t3 = 0.f;
        #pragma unroll
        for (int k = 0; k < 64; ++k) {
            float4 w = w4[k];
            t0 = fmaf(w.x, w.x, t0); t1 = fmaf(w.y, w.y, t1);
            t2 = fmaf(w.z, w.z, t2); t3 = fmaf(w.w, w.w, t3);
        }
        const float lmn = (t0 + t1) + (t2 + t3);

        float d0 = 0.f, d1 = 0.f, d2 = 0.f, d3 = 0.f;
        #pragma unroll
        for (int k = 0; k < LF4; ++k) {
            float4 v = slab[k * TPB + tid];
            float4 w = w4[k];
            d0 = fmaf(v.x, w.x, d0); d1 = fmaf(v.y, w.y, d1);
            d2 = fmaf(v.z, w.z, d2); d3 = fmaf(v.w, w.w, d3);
        }
        #pragma unroll
        for (int k = 0; k < RF4; ++k) {
            float4 v = p[k];
            float4 w = w4[LF4 + k];
            d0 = fmaf(v.x, w.x, d0); d1 = fmaf(v.y, w.y, d1);
            d2 = fmaf(v.z, w.z, d2); d3 = fmaf(v.w, w.w, d3);
        }
        const float dot  = (d0 + d1) + (d2 + d3);
        const float diff = fmaxf(my_xn + lmn - 2.f * dot, 1e-10f);
        const float fac  = fmaxf(1.f + c * my_xn + c * lmn, 1e-6f);
        const float d    = sqrtf(diff) * sqrtf(fac);

        // fused witness: landmark POSITION s-1, ascending order, strict '<'
        if (d < b1v)      { b2v = b1v; b2i = b1i; b1v = d; b1i = s - 1; }
        else if (d < b2v) { b2v = d; b2i = s - 1; }

        if (s == L_) break;

        min_d = fminf(min_d, d);

        // wave argmax (tie -> lower n)
        float v = min_d; int i = n;
        #pragma unroll
        for (int off = 32; off >= 1; off >>= 1) {
            float ov = __shfl_down(v, off);
            int   oi = __shfl_down(i, off);
            if (ov > v || (ov == v && oi < i)) { v = ov; i = oi; }
        }
        if ((tid & 63) == 0) { wval[tid >> 6] = v; widx[tid >> 6] = i; }
        __syncthreads();

        if (tid < 64) {   // wave 0: reduce block, publish ONE u64, poll, reduce
            v = (tid < 8) ? wval[tid] : -__builtin_inff();
            i = (tid < 8) ? widx[tid] : 0x7FFFFFFF;
            #pragma unroll
            for (int off = 4; off >= 1; off >>= 1) {
                float ov = __shfl_down(v, off);
                int   oi = __shfl_down(i, off);
                if (ov > v || (ov == v && oi < i)) { v = ov; i = oi; }
            }
            const int base = (b * 64 + s) * 32;
            if (tid == 0) {
                // d > 0 always (sqrt(>=1e-10 * >=1e-6)) -> key != 0
                const unsigned long long key =
                    ((unsigned long long)__float_as_uint(v) << 32) |
                    (unsigned long long)(0xFFFFFFFFu - (unsigned)i);
                __hip_atomic_store(&slot[base + wib], key,
                                   __ATOMIC_RELAXED, __HIP_MEMORY_SCOPE_AGENT);
            }
            // single-phase: poll all 32 slots (lane l -> slot l), no fences
            unsigned long long myk;
            for (;;) {
                myk = __hip_atomic_load(&slot[base + (tid & 31)],
                                        __ATOMIC_RELAXED, __HIP_MEMORY_SCOPE_AGENT);
                if (__all(myk != 0ull)) break;
                __builtin_amdgcn_s_sleep(1);
            }
            unsigned long long k = myk;   // max over 32 distinct keys
            #pragma unroll
            for (int off = 32; off >= 1; off >>= 1) {
                unsigned long long ok = __shfl_down(k, off);
                if (ok > k) k = ok;
            }
            if (tid == 0)
                s_next = (int)(0xFFFFFFFFu - (unsigned)(k & 0xFFFFFFFFull));
        }
        __syncthreads();
        lm = s_next;
    }

    // emit my edge (top-2 landmark positions) into LDS bitmask
    {
        const int lo = min(b1i, b2i), hi = max(b1i, b2i);
        const int bitpos = lo * 64 + hi;
        atomicOr(&lmask[bitpos >> 5], 1u << (bitpos & 31));
    }
    __syncthreads();
    if (tid < 128) {
        unsigned w = lmask[tid];
        if (w) atomicOr(&gadj[b * 128 + tid], w);   // agent-scope RMW at LLC
    }
    __syncthreads();

    if (tid == 0) {
        __threadfence();
        unsigned prev = atomicAdd(&cnt[b], 1u);
        s_lead = (prev == 31u) ? 1 : 0;
    }
    __syncthreads();
    if (!s_lead) return;

    // ---- leader WG (last arriver): finalize this batch ----
    __threadfence();
    if (tid < 128) lmask[tid] = atomicOr(&gadj[b * 128 + tid], 0u);  // coherent read
    __syncthreads();

    unsigned long long m = 0ull;
    if (tid < 64) {
        m = ((unsigned long long)lmask[tid * 2 + 1] << 32) | lmask[tid * 2];
        for (int j = 0; j < 64; ++j)           // symmetrize: column bits
            if (lmask[j * 2 + (tid >> 5)] & (1u << (tid & 31))) m |= 1ull << j;
        labels[tid] = tid;
    }
    __syncthreads();

    for (int it = 0; it < 64; ++it) {          // synchronous min-label propagation
        int mn = 0;
        if (tid < 64) {
            mn = labels[tid];
            unsigned long long mm = m;
            while (mm) {
                int j = __ffsll(mm) - 1;
                int lj = labels[j];
                mn = mn < lj ? mn : lj;
                mm &= mm - 1;
            }
        }
        __syncthreads();
        if (tid < 64) labels[tid] = mn;
        __syncthreads();
    }

    if (tid < 64) {
        unsigned long long hi_mask = (tid < 63) ? (~0ull << (tid + 1)) : 0ull;
        int myedges = __popcll(m & hi_mask);
        int mycomp  = (labels[tid] == tid) ? 1 : 0;
        #pragma unroll
        for (int off = 32; off >= 1; off >>= 1) {
            myedges += __shfl_down(myedges, off);
            mycomp  += __shfl_down(mycomp, off);
        }
        if (tid == 0) {
            float beta0 = (float)mycomp;
            float beta1 = (float)(myedges - (64 - mycomp));
            out[b]      = beta0;
            out[8 + b]  = beta1;
            out[16 + b] = beta0 / 64.f;
            out[24 + b] = (beta1 > 3.f) ? 1.f : 0.f;
        }
    }
}

// ---------------------------------------------------------------------------
extern "C" void kernel_launch(void* const* d_in, const int* in_sizes, int n_in,
                              void* d_out, int out_size, void* d_ws, size_t ws_size,
                              hipStream_t stream)
{
    const float* emb = (const float*)d_in[0];
    const float* cs  = (const float*)d_in[1];
    float* out = (float*)d_out;

    char* ws = (char*)d_ws;
    unsigned long long* slot = (unsigned long long*)(ws);
    unsigned int*       gadj = (unsigned int*)(ws + 131072);
    unsigned int*       cnt  = (unsigned int*)(ws + 135168);

    hipLaunchKernelGGL(init_kernel, dim3(34), dim3(1024), 0, stream,
                       (unsigned int*)ws);
    hipLaunchKernelGGL(fps_all_kernel, dim3(256), dim3(TPB), 0, stream,
                       emb, cs, slot, gadj, cnt, out);
}

// Round 12
// 617.552 us; speedup vs baseline: 1.1794x; 1.1794x over previous
//
#include <hip/hip_runtime.h>

static constexpr int B_ = 8;
static constexpr int N_ = 16384;
static constexpr int D_ = 256;
static constexpr int L_ = 64;

static constexpr int TPB = 512;       // 256 WGs x 512 thr, 1 WG/CU (LDS-forced), 1 point/thread
static constexpr int LF4 = 18;        // dims 0..71 in LDS
static constexpr int RF4 = 64 - LF4;  // dims 72..255 in VGPRs (46 float4)

// ws layout (init zeroes 208896 B every call; ws poisoned 0xAA once):
//   slot u64[8][64][32] @ 0       (131072 B)  packed (dist_bits<<32)|(~n) per WG per step
//   pay  u32[8][64][32] @ 131072  ( 65536 B)  xn_bits^0x80000000 of that candidate
//   gadj u32[8][128]    @ 196608  (  4096 B)  64x64 edge bitmask per batch
//   cnt  u32[8]         @ 200704  (    32 B)  finalize arrival counters

__global__ void __launch_bounds__(1024)
init_kernel(unsigned int* __restrict__ z)
{
    z[blockIdx.x * 1024 + threadIdx.x] = 0u;   // grid 51 -> 208896 B
}

// ---------------------------------------------------------------------------
// Fused FPS scan + witness + finalize. Single-phase barrier with RMW publish:
//   per step each WG publishes pay (enc norm) then key via atomicExch —
//   agent-scope RMWs execute AT THE LLC immediately (per-XCD L2s are not
//   coherent, so the hw routes RMWs to the coherence point), eliminating the
//   dirty-line eviction delay suspected of costing ~8 us/step with plain
//   relaxed stores. Pollers use relaxed agent loads (r8/r9-proven cheap).
// Norm rides in pay (r5/r8/r10-validated carry). Scalar landmark row (r10).
// All FMA/compare orders bit-identical to the r5..r10-validated kernels.
// ---------------------------------------------------------------------------
__global__ __attribute__((amdgpu_flat_work_group_size(512, 512),
                          amdgpu_waves_per_eu(2, 2)))
void fps_all_kernel(const float* __restrict__ emb, const float* __restrict__ csp,
                    unsigned long long* __restrict__ slot,
                    unsigned int* __restrict__ pay,
                    unsigned int* __restrict__ gadj,
                    unsigned int* __restrict__ cnt,
                    float* __restrict__ out)
{
    const int wg  = blockIdx.x;        // 0..255
    const int b   = wg >> 5;           // batch (32 WGs/batch)
    const int wib = wg & 31;
    const int tid = threadIdx.x;
    const int n   = (wib << 9) + tid;  // my point
    const float c = fabsf(csp[0]);

    __shared__ float4 slab[LF4 * TPB];          // 147456 B resident slice
    __shared__ float wval[8];
    __shared__ int   widx[8];
    __shared__ float wxn[8];
    __shared__ int   s_next;
    __shared__ float s_lmn;
    __shared__ int   s_lead;
    __shared__ unsigned int lmask[128];
    __shared__ int   labels[64];

    if (tid < 128) lmask[tid] = 0u;

    const float4* __restrict__ pt = (const float4*)(emb + (size_t)(b * N_ + n) * D_);

    // resident load + norm (sequential 4-acc over k=0..63, matches r1..r10)
    float4 p[RF4];
    float s0 = 0.f, s1 = 0.f, s2 = 0.f, s3 = 0.f;
    #pragma unroll
    for (int k = 0; k < LF4; ++k) {
        float4 v = pt[k];
        slab[k * TPB + tid] = v;
        s0 = fmaf(v.x, v.x, s0); s1 = fmaf(v.y, v.y, s1);
        s2 = fmaf(v.z, v.z, s2); s3 = fmaf(v.w, v.w, s3);
    }
    #pragma unroll
    for (int k = 0; k < RF4; ++k) {
        float4 v = pt[LF4 + k];
        p[k] = v;
        s0 = fmaf(v.x, v.x, s0); s1 = fmaf(v.y, v.y, s1);
        s2 = fmaf(v.z, v.z, s2); s3 = fmaf(v.w, v.w, s3);
    }
    const float my_xn = (s0 + s1) + (s2 + s3);

    float min_d = __builtin_inff();
    float b1v = __builtin_inff(), b2v = __builtin_inff();
    int   b1i = 0, b2i = 0;
    int   lm    = 0;      // landmark 0 = point 0
    float lmn_c = 0.f;

    #pragma unroll 1
    for (int s = 1; s <= L_; ++s) {
        // uniform (SGPR) pointer to landmark row s-1 — scalar-load path (r10)
        const int lmU = __builtin_amdgcn_readfirstlane(lm);
        const float4* __restrict__ w4 =
            (const float4*)(emb + (size_t)(b * N_ + lmU) * D_);

        float lmn;
        if (s == 1) {
            // landmark 0's norm computed locally (same 4-acc k-ascending order)
            float t0 = 0.f, t1 = 0.f, t2 = 0.f, t3 = 0.f;
            #pragma unroll
            for (int k = 0; k < 64; ++k) {
                float4 w = w4[k];
                t0 = fmaf(w.x, w.x, t0); t1 = fmaf(w.y, w.y, t1);
                t2 = fmaf(w.z, w.z, t2); t3 = fmaf(w.w, w.w, t3);
            }
            lmn = (t0 + t1) + (t2 + t3);
        } else {
            lmn = lmn_c;   // winner's xn carried through the barrier (r5..r10)
        }

        float d0 = 0.f, d1 = 0.f, d2 = 0.f, d3 = 0.f;
        #pragma unroll
        for (int k = 0; k < LF4; ++k) {
            float4 v = slab[k * TPB + tid];
            float4 w = w4[k];
            d0 = fmaf(v.x, w.x, d0); d1 = fmaf(v.y, w.y, d1);
            d2 = fmaf(v.z, w.z, d2); d3 = fmaf(v.w, w.w, d3);
        }
        #pragma unroll
        for (int k = 0; k < RF4; ++k) {
            float4 v = p[k];
            float4 w = w4[LF4 + k];
            d0 = fmaf(v.x, w.x, d0); d1 = fmaf(v.y, w.y, d1);
            d2 = fmaf(v.z, w.z, d2); d3 = fmaf(v.w, w.w, d3);
        }
        const float dot  = (d0 + d1) + (d2 + d3);
        const float diff = fmaxf(my_xn + lmn - 2.f * dot, 1e-10f);
        const float fac  = fmaxf(1.f + c * my_xn + c * lmn, 1e-6f);
        const float d    = sqrtf(diff) * sqrtf(fac);

        // fused witness: landmark POSITION s-1, ascending order, strict '<'
        if (d < b1v)      { b2v = b1v; b2i = b1i; b1v = d; b1i = s - 1; }
        else if (d < b2v) { b2v = d; b2i = s - 1; }

        if (s == L_) break;

        min_d = fminf(min_d, d);

        // wave argmax (tie -> lower n), carrying candidate's xn
        float v = min_d; int i = n; float x = my_xn;
        #pragma unroll
        for (int off = 32; off >= 1; off >>= 1) {
            float ov = __shfl_down(v, off);
            int   oi = __shfl_down(i, off);
            float ox = __shfl_down(x, off);
            if (ov > v || (ov == v && oi < i)) { v = ov; i = oi; x = ox; }
        }
        if ((tid & 63) == 0) {
            const int w = tid >> 6;
            wval[w] = v; widx[w] = i; wxn[w] = x;
        }
        __syncthreads();

        if (tid < 64) {   // wave 0: publish via RMW, poll, reduce, broadcast
            v = (tid < 8) ? wval[tid] : -__builtin_inff();
            i = (tid < 8) ? widx[tid] : 0x7FFFFFFF;
            x = (tid < 8) ? wxn[tid]  : 0.f;
            #pragma unroll
            for (int off = 4; off >= 1; off >>= 1) {
                float ov = __shfl_down(v, off);
                int   oi = __shfl_down(i, off);
                float ox = __shfl_down(x, off);
                if (ov > v || (ov == v && oi < i)) { v = ov; i = oi; x = ox; }
            }
            const int base = (b * 64 + s) * 32;
            if (tid == 0) {
                const unsigned long long key =
                    ((unsigned long long)__float_as_uint(v) << 32) |
                    (unsigned long long)(0xFFFFFFFFu - (unsigned)i);
                const unsigned enc = __float_as_uint(x) ^ 0x80000000u;  // never 0
                atomicExch(&pay[base + wib], enc);          // RMW -> lands at LLC now
                asm volatile("s_waitcnt vmcnt(0)" ::: "memory");  // enc before key
                atomicExch(&slot[base + wib], (unsigned long long)key);
            }
            // poll both words with relaxed agent loads; zeros -> retry
            unsigned long long myk; unsigned mye;
            for (;;) {
                myk = __hip_atomic_load(&slot[base + (tid & 31)],
                                        __ATOMIC_RELAXED, __HIP_MEMORY_SCOPE_AGENT);
                mye = __hip_atomic_load(&pay[base + (tid & 31)],
                                        __ATOMIC_RELAXED, __HIP_MEMORY_SCOPE_AGENT);
                if (__all((myk != 0ull) && (mye != 0u))) break;
                __builtin_amdgcn_s_sleep(1);
            }
            // max-reduce 32 distinct keys, carrying enc (lanes 32..63 duplicate)
            unsigned long long k = myk; unsigned e = mye;
            #pragma unroll
            for (int off = 32; off >= 1; off >>= 1) {
                unsigned long long ok = __shfl_down(k, off);
                unsigned           oe = __shfl_down(e, off);
                if (ok > k) { k = ok; e = oe; }
            }
            if (tid == 0) {
                s_next = (int)(0xFFFFFFFFu - (unsigned)(k & 0xFFFFFFFFull));
                s_lmn  = __uint_as_float(e ^ 0x80000000u);
            }
        }
        __syncthreads();
        lm    = s_next;
        lmn_c = s_lmn;
    }

    // emit my edge (top-2 landmark positions) into LDS bitmask
    {
        const int lo = min(b1i, b2i), hi = max(b1i, b2i);
        const int bitpos = lo * 64 + hi;
        atomicOr(&lmask[bitpos >> 5], 1u << (bitpos & 31));
    }
    __syncthreads();
    if (tid < 128) {
        unsigned w = lmask[tid];
        if (w) atomicOr(&gadj[b * 128 + tid], w);   // agent-scope RMW at LLC
    }
    __syncthreads();

    if (tid == 0) {
        __threadfence();
        unsigned prev = atomicAdd(&cnt[b], 1u);
        s_lead = (prev == 31u) ? 1 : 0;
    }
    __syncthreads();
    if (!s_lead) return;

    // ---- leader WG (last arriver): finalize this batch ----
    __threadfence();
    if (tid < 128) lmask[tid] = atomicOr(&gadj[b * 128 + tid], 0u);  // coherent read
    __syncthreads();

    unsigned long long m = 0ull;
    if (tid < 64) {
        m = ((unsigned long long)lmask[tid * 2 + 1] << 32) | lmask[tid * 2];
        for (int j = 0; j < 64; ++j)           // symmetrize: column bits
            if (lmask[j * 2 + (tid >> 5)] & (1u << (tid & 31))) m |= 1ull << j;
        labels[tid] = tid;
    }
    __syncthreads();

    for (int it = 0; it < 64; ++it) {          // synchronous min-label propagation
        int mn = 0;
        if (tid < 64) {
            mn = labels[tid];
            unsigned long long mm = m;
            while (mm) {
                int j = __ffsll(mm) - 1;
                int lj = labels[j];
                mn = mn < lj ? mn : lj;
                mm &= mm - 1;
            }
        }
        __syncthreads();
        if (tid < 64) labels[tid] = mn;
        __syncthreads();
    }

    if (tid < 64) {
        unsigned long long hi_mask = (tid < 63) ? (~0ull << (tid + 1)) : 0ull;
        int myedges = __popcll(m & hi_mask);
        int mycomp  = (labels[tid] == tid) ? 1 : 0;
        #pragma unroll
        for (int off = 32; off >= 1; off >>= 1) {
            myedges += __shfl_down(myedges, off);
            mycomp  += __shfl_down(mycomp, off);
        }
        if (tid == 0) {
            float beta0 = (float)mycomp;
            float beta1 = (float)(myedges - (64 - mycomp));
            out[b]      = beta0;
            out[8 + b]  = beta1;
            out[16 + b] = beta0 / 64.f;
            out[24 + b] = (beta1 > 3.f) ? 1.f : 0.f;
        }
    }
}

// ---------------------------------------------------------------------------
extern "C" void kernel_launch(void* const* d_in, const int* in_sizes, int n_in,
                              void* d_out, int out_size, void* d_ws, size_t ws_size,
                              hipStream_t stream)
{
    const float* emb = (const float*)d_in[0];
    const float* cs  = (const float*)d_in[1];
    float* out = (float*)d_out;

    char* ws = (char*)d_ws;
    unsigned long long* slot = (unsigned long long*)(ws);
    unsigned int*       pay  = (unsigned int*)(ws + 131072);
    unsigned int*       gadj = (unsigned int*)(ws + 196608);
    unsigned int*       cnt  = (unsigned int*)(ws + 200704);

    hipLaunchKernelGGL(init_kernel, dim3(51), dim3(1024), 0, stream,
                       (unsigned int*)ws);
    hipLaunchKernelGGL(fps_all_kernel, dim3(256), dim3(TPB), 0, stream,
                       emb, cs, slot, pay, gadj, cnt, out);
}

// Round 13
// 608.708 us; speedup vs baseline: 1.1965x; 1.0145x over previous
//
#include <hip/hip_runtime.h>

static constexpr int B_ = 8;
static constexpr int N_ = 16384;
static constexpr int D_ = 256;
static constexpr int L_ = 64;

static constexpr int TPB = 512;       // 256 WGs x 512 thr, 1 WG/CU (LDS-forced), 1 point/thread
static constexpr int LF4 = 18;        // dims 0..71 in LDS
static constexpr int RF4 = 64 - LF4;  // dims 72..255 in VGPRs (46 float4)

// ws layout (init zeroes 266240 B every call; ws poisoned 0xAA once):
//   rec  u64[8][64][32][2] @ 0      (262144 B)  {key, enc64} per WG per step, same 16B line
//   gadj u32[8][128]       @ 262144 (  4096 B)  64x64 edge bitmask per batch
//   cnt  u32[8]            @ 266240 (    32 B)  finalize arrival counters

__global__ void __launch_bounds__(1024)
init_kernel(unsigned int* __restrict__ z)
{
    z[blockIdx.x * 1024 + threadIdx.x] = 0u;   // grid 66 -> 270336 B
}

// ---------------------------------------------------------------------------
// Fused FPS scan + witness + finalize. Single-phase barrier, hot poll:
//   publish: rec[1]=enc64 (relaxed), vmcnt(0), rec[0]=key (relaxed) — both in
//   ONE 16B-aligned record (same cache line, r8-proven ordering);
//   poll: wave 0 lane l hot-loads record l's two u64s (adjacent, parallel,
//   no s_sleep) until all keys and encs nonzero, then max-reduces carrying
//   enc. Zero-init sentinels make any staleness a benign retry.
// All FMA/compare orders bit-identical to the r5..r12-validated kernels.
// ---------------------------------------------------------------------------
__global__ __attribute__((amdgpu_flat_work_group_size(512, 512),
                          amdgpu_waves_per_eu(2, 2)))
void fps_all_kernel(const float* __restrict__ emb, const float* __restrict__ csp,
                    unsigned long long* __restrict__ rec,
                    unsigned int* __restrict__ gadj,
                    unsigned int* __restrict__ cnt,
                    float* __restrict__ out)
{
    const int wg  = blockIdx.x;        // 0..255
    const int b   = wg >> 5;           // batch (32 WGs/batch)
    const int wib = wg & 31;
    const int tid = threadIdx.x;
    const int n   = (wib << 9) + tid;  // my point
    const float c = fabsf(csp[0]);

    __shared__ float4 slab[LF4 * TPB];          // 147456 B resident slice
    __shared__ float wval[8];
    __shared__ int   widx[8];
    __shared__ float wxn[8];
    __shared__ int   s_next;
    __shared__ float s_lmn;
    __shared__ int   s_lead;
    __shared__ unsigned int lmask[128];
    __shared__ int   labels[64];

    if (tid < 128) lmask[tid] = 0u;

    const float4* __restrict__ pt = (const float4*)(emb + (size_t)(b * N_ + n) * D_);

    // resident load + norm (sequential 4-acc over k=0..63, matches r1..r12)
    float4 p[RF4];
    float s0 = 0.f, s1 = 0.f, s2 = 0.f, s3 = 0.f;
    #pragma unroll
    for (int k = 0; k < LF4; ++k) {
        float4 v = pt[k];
        slab[k * TPB + tid] = v;
        s0 = fmaf(v.x, v.x, s0); s1 = fmaf(v.y, v.y, s1);
        s2 = fmaf(v.z, v.z, s2); s3 = fmaf(v.w, v.w, s3);
    }
    #pragma unroll
    for (int k = 0; k < RF4; ++k) {
        float4 v = pt[LF4 + k];
        p[k] = v;
        s0 = fmaf(v.x, v.x, s0); s1 = fmaf(v.y, v.y, s1);
        s2 = fmaf(v.z, v.z, s2); s3 = fmaf(v.w, v.w, s3);
    }
    const float my_xn = (s0 + s1) + (s2 + s3);

    float min_d = __builtin_inff();
    float b1v = __builtin_inff(), b2v = __builtin_inff();
    int   b1i = 0, b2i = 0;
    int   lm    = 0;      // landmark 0 = point 0
    float lmn_c = 0.f;

    #pragma unroll 1
    for (int s = 1; s <= L_; ++s) {
        // uniform (SGPR) pointer to landmark row s-1 — scalar-load path (r10)
        const int lmU = __builtin_amdgcn_readfirstlane(lm);
        const float4* __restrict__ w4 =
            (const float4*)(emb + (size_t)(b * N_ + lmU) * D_);

        float lmn;
        if (s == 1) {
            // landmark 0's norm computed locally (same 4-acc k-ascending order)
            float t0 = 0.f, t1 = 0.f, t2 = 0.f, t3 = 0.f;
            #pragma unroll
            for (int k = 0; k < 64; ++k) {
                float4 w = w4[k];
                t0 = fmaf(w.x, w.x, t0); t1 = fmaf(w.y, w.y, t1);
                t2 = fmaf(w.z, w.z, t2); t3 = fmaf(w.w, w.w, t3);
            }
            lmn = (t0 + t1) + (t2 + t3);
        } else {
            lmn = lmn_c;   // winner's xn carried through the barrier (r5..r12)
        }

        float d0 = 0.f, d1 = 0.f, d2 = 0.f, d3 = 0.f;
        #pragma unroll
        for (int k = 0; k < LF4; ++k) {
            float4 v = slab[k * TPB + tid];
            float4 w = w4[k];
            d0 = fmaf(v.x, w.x, d0); d1 = fmaf(v.y, w.y, d1);
            d2 = fmaf(v.z, w.z, d2); d3 = fmaf(v.w, w.w, d3);
        }
        #pragma unroll
        for (int k = 0; k < RF4; ++k) {
            float4 v = p[k];
            float4 w = w4[LF4 + k];
            d0 = fmaf(v.x, w.x, d0); d1 = fmaf(v.y, w.y, d1);
            d2 = fmaf(v.z, w.z, d2); d3 = fmaf(v.w, w.w, d3);
        }
        const float dot  = (d0 + d1) + (d2 + d3);
        const float diff = fmaxf(my_xn + lmn - 2.f * dot, 1e-10f);
        const float fac  = fmaxf(1.f + c * my_xn + c * lmn, 1e-6f);
        const float d    = sqrtf(diff) * sqrtf(fac);

        // fused witness: landmark POSITION s-1, ascending order, strict '<'
        if (d < b1v)      { b2v = b1v; b2i = b1i; b1v = d; b1i = s - 1; }
        else if (d < b2v) { b2v = d; b2i = s - 1; }

        if (s == L_) break;

        min_d = fminf(min_d, d);

        // wave argmax (tie -> lower n), carrying candidate's xn
        float v = min_d; int i = n; float x = my_xn;
        #pragma unroll
        for (int off = 32; off >= 1; off >>= 1) {
            float ov = __shfl_down(v, off);
            int   oi = __shfl_down(i, off);
            float ox = __shfl_down(x, off);
            if (ov > v || (ov == v && oi < i)) { v = ov; i = oi; x = ox; }
        }
        if ((tid & 63) == 0) {
            const int w = tid >> 6;
            wval[w] = v; widx[w] = i; wxn[w] = x;
        }
        __syncthreads();

        if (tid < 64) {   // wave 0: publish, hot-poll, reduce, broadcast
            v = (tid < 8) ? wval[tid] : -__builtin_inff();
            i = (tid < 8) ? widx[tid] : 0x7FFFFFFF;
            x = (tid < 8) ? wxn[tid]  : 0.f;
            #pragma unroll
            for (int off = 4; off >= 1; off >>= 1) {
                float ov = __shfl_down(v, off);
                int   oi = __shfl_down(i, off);
                float ox = __shfl_down(x, off);
                if (ov > v || (ov == v && oi < i)) { v = ov; i = oi; x = ox; }
            }
            const size_t base = ((size_t)(b * 64 + s) * 32) * 2;   // u64 index
            if (tid == 0) {
                const unsigned long long key =
                    ((unsigned long long)__float_as_uint(v) << 32) |
                    (unsigned long long)(0xFFFFFFFFu - (unsigned)i);
                const unsigned long long enc64 =
                    (unsigned long long)(__float_as_uint(x) ^ 0x80000000u); // never 0
                __hip_atomic_store(&rec[base + wib * 2 + 1], enc64,
                                   __ATOMIC_RELAXED, __HIP_MEMORY_SCOPE_AGENT);
                asm volatile("s_waitcnt vmcnt(0)" ::: "memory");  // enc before key
                __hip_atomic_store(&rec[base + wib * 2 + 0], key,
                                   __ATOMIC_RELAXED, __HIP_MEMORY_SCOPE_AGENT);
            }
            // hot poll: lane l -> record l (two adjacent u64s, one line-fetch)
            unsigned long long myk, mye;
            for (;;) {
                myk = __hip_atomic_load(&rec[base + (tid & 31) * 2 + 0],
                                        __ATOMIC_RELAXED, __HIP_MEMORY_SCOPE_AGENT);
                mye = __hip_atomic_load(&rec[base + (tid & 31) * 2 + 1],
                                        __ATOMIC_RELAXED, __HIP_MEMORY_SCOPE_AGENT);
                if (__all((myk != 0ull) && (mye != 0ull))) break;
            }
            // max-reduce 32 distinct keys, carrying enc (lanes 32..63 duplicate)
            unsigned long long k = myk, e = mye;
            #pragma unroll
            for (int off = 32; off >= 1; off >>= 1) {
                unsigned long long ok = __shfl_down(k, off);
                unsigned long long oe = __shfl_down(e, off);
                if (ok > k) { k = ok; e = oe; }
            }
            if (tid == 0) {
                s_next = (int)(0xFFFFFFFFu - (unsigned)(k & 0xFFFFFFFFull));
                s_lmn  = __uint_as_float((unsigned)e ^ 0x80000000u);
            }
        }
        __syncthreads();
        lm    = s_next;
        lmn_c = s_lmn;
    }

    // emit my edge (top-2 landmark positions) into LDS bitmask
    {
        const int lo = min(b1i, b2i), hi = max(b1i, b2i);
        const int bitpos = lo * 64 + hi;
        atomicOr(&lmask[bitpos >> 5], 1u << (bitpos & 31));
    }
    __syncthreads();
    if (tid < 128) {
        unsigned w = lmask[tid];
        if (w) atomicOr(&gadj[b * 128 + tid], w);   // agent-scope RMW at LLC
    }
    __syncthreads();

    if (tid == 0) {
        __threadfence();
        unsigned prev = atomicAdd(&cnt[b], 1u);
        s_lead = (prev == 31u) ? 1 : 0;
    }
    __syncthreads();
    if (!s_lead) return;

    // ---- leader WG (last arriver): finalize this batch ----
    __threadfence();
    if (tid < 128) lmask[tid] = atomicOr(&gadj[b * 128 + tid], 0u);  // coherent read
    __syncthreads();

    unsigned long long m = 0ull;
    if (tid < 64) {
        m = ((unsigned long long)lmask[tid * 2 + 1] << 32) | lmask[tid * 2];
        for (int j = 0; j < 64; ++j)           // symmetrize: column bits
            if (lmask[j * 2 + (tid >> 5)] & (1u << (tid & 31))) m |= 1ull << j;
        labels[tid] = tid;
    }
    __syncthreads();

    for (int it = 0; it < 64; ++it) {          // synchronous min-label propagation
        int mn = 0;
        if (tid < 64) {
            mn = labels[tid];
            unsigned long long mm = m;
            while (mm) {
                int j = __ffsll(mm) - 1;
                int lj = labels[j];
                mn = mn < lj ? mn : lj;
                mm &= mm - 1;
            }
        }
        __syncthreads();
        if (tid < 64) labels[tid] = mn;
        __syncthreads();
    }

    if (tid < 64) {
        unsigned long long hi_mask = (tid < 63) ? (~0ull << (tid + 1)) : 0ull;
        int myedges = __popcll(m & hi_mask);
        int mycomp  = (labels[tid] == tid) ? 1 : 0;
        #pragma unroll
        for (int off = 32; off >= 1; off >>= 1) {
            myedges += __shfl_down(myedges, off);
            mycomp  += __shfl_down(mycomp, off);
        }
        if (tid == 0) {
            float beta0 = (float)mycomp;
            float beta1 = (float)(myedges - (64 - mycomp));
            out[b]      = beta0;
            out[8 + b]  = beta1;
            out[16 + b] = beta0 / 64.f;
            out[24 + b] = (beta1 > 3.f) ? 1.f : 0.f;
        }
    }
}

// ---------------------------------------------------------------------------
extern "C" void kernel_launch(void* const* d_in, const int* in_sizes, int n_in,
                              void* d_out, int out_size, void* d_ws, size_t ws_size,
                              hipStream_t stream)
{
    const float* emb = (const float*)d_in[0];
    const float* cs  = (const float*)d_in[1];
    float* out = (float*)d_out;

    char* ws = (char*)d_ws;
    unsigned long long* rec  = (unsigned long long*)(ws);
    unsigned int*       gadj = (unsigned int*)(ws + 262144);
    unsigned int*       cnt  = (unsigned int*)(ws + 266240);

    hipLaunchKernelGGL(init_kernel, dim3(66), dim3(1024), 0, stream,
                       (unsigned int*)ws);
    hipLaunchKernelGGL(fps_all_kernel, dim3(256), dim3(TPB), 0, stream,
                       emb, cs, rec, gadj, cnt, out);
}

// Round 14
// 550.070 us; speedup vs baseline: 1.3241x; 1.1066x over previous
//
#include <hip/hip_runtime.h>

static constexpr int B_ = 8;
static constexpr int N_ = 16384;
static constexpr int D_ = 256;
static constexpr int L_ = 64;

static constexpr int TPB = 512;       // 256 WGs x 512 thr, 1 WG/CU (LDS-forced), 1 point/thread
static constexpr int LF4 = 18;        // dims 0..71 in LDS
static constexpr int RF4 = 64 - LF4;  // dims 72..255 in VGPRs (46 float4)

// ws layout (init zeroes 266272 B every call; ws poisoned 0xAA once):
//   rec  u64[8][64][32][2] @ 0      (262144 B)  {key, enc64} per WG per step, same 16B line
//   gadj u32[8][128]       @ 262144 (  4096 B)  64x64 edge bitmask per batch
//   cnt  u32[8]            @ 266240 (    32 B)  finalize arrival counters

__global__ void __launch_bounds__(1024)
init_kernel(unsigned int* __restrict__ z)
{
    z[blockIdx.x * 1024 + threadIdx.x] = 0u;   // grid 66 -> 270336 B
}

// ---------------------------------------------------------------------------
// Fused FPS scan + witness + finalize. Single-phase barrier, hot poll,
// UNORDERED parallel publish: key and enc are stored back-to-back relaxed
// (no vmcnt between — each word is single-writer monotone 0->final and the
// poller retries until BOTH are nonzero, so inter-store order is irrelevant;
// the r5..r13 vmcnt(0) was a serialized LLC round trip per step for nothing).
// Batch = wg&7: under round-robin dispatch all 32 WGs of a batch share one
// XCD (shorter rendezvous path); correctness is mapping-independent since
// all sync is agent-scope at the LLC.
// All FMA/compare orders bit-identical to the r5..r13-validated kernels.
// ---------------------------------------------------------------------------
__global__ __attribute__((amdgpu_flat_work_group_size(512, 512),
                          amdgpu_waves_per_eu(2, 2)))
void fps_all_kernel(const float* __restrict__ emb, const float* __restrict__ csp,
                    unsigned long long* __restrict__ rec,
                    unsigned int* __restrict__ gadj,
                    unsigned int* __restrict__ cnt,
                    float* __restrict__ out)
{
    const int wg  = blockIdx.x;        // 0..255
    const int b   = wg & 7;            // batch == presumed XCD (round-robin)
    const int wib = wg >> 3;           // 0..31 within batch
    const int tid = threadIdx.x;
    const int n   = (wib << 9) + tid;  // my point
    const float c = fabsf(csp[0]);

    __shared__ float4 slab[LF4 * TPB];          // 147456 B resident slice
    __shared__ float wval[8];
    __shared__ int   widx[8];
    __shared__ float wxn[8];
    __shared__ int   s_next;
    __shared__ float s_lmn;
    __shared__ int   s_lead;
    __shared__ unsigned int lmask[128];
    __shared__ int   labels[64];

    if (tid < 128) lmask[tid] = 0u;

    const float4* __restrict__ pt = (const float4*)(emb + (size_t)(b * N_ + n) * D_);

    // resident load + norm (sequential 4-acc over k=0..63, matches r1..r13)
    float4 p[RF4];
    float s0 = 0.f, s1 = 0.f, s2 = 0.f, s3 = 0.f;
    #pragma unroll
    for (int k = 0; k < LF4; ++k) {
        float4 v = pt[k];
        slab[k * TPB + tid] = v;
        s0 = fmaf(v.x, v.x, s0); s1 = fmaf(v.y, v.y, s1);
        s2 = fmaf(v.z, v.z, s2); s3 = fmaf(v.w, v.w, s3);
    }
    #pragma unroll
    for (int k = 0; k < RF4; ++k) {
        float4 v = pt[LF4 + k];
        p[k] = v;
        s0 = fmaf(v.x, v.x, s0); s1 = fmaf(v.y, v.y, s1);
        s2 = fmaf(v.z, v.z, s2); s3 = fmaf(v.w, v.w, s3);
    }
    const float my_xn = (s0 + s1) + (s2 + s3);

    float min_d = __builtin_inff();
    float b1v = __builtin_inff(), b2v = __builtin_inff();
    int   b1i = 0, b2i = 0;
    int   lm    = 0;      // landmark 0 = point 0
    float lmn_c = 0.f;

    #pragma unroll 1
    for (int s = 1; s <= L_; ++s) {
        // uniform (SGPR) pointer to landmark row s-1 — scalar-load path (r10)
        const int lmU = __builtin_amdgcn_readfirstlane(lm);
        const float4* __restrict__ w4 =
            (const float4*)(emb + (size_t)(b * N_ + lmU) * D_);

        float lmn;
        if (s == 1) {
            // landmark 0's norm computed locally (same 4-acc k-ascending order)
            float t0 = 0.f, t1 = 0.f, t2 = 0.f, t3 = 0.f;
            #pragma unroll
            for (int k = 0; k < 64; ++k) {
                float4 w = w4[k];
                t0 = fmaf(w.x, w.x, t0); t1 = fmaf(w.y, w.y, t1);
                t2 = fmaf(w.z, w.z, t2); t3 = fmaf(w.w, w.w, t3);
            }
            lmn = (t0 + t1) + (t2 + t3);
        } else {
            lmn = lmn_c;   // winner's xn carried through the barrier (r5..r13)
        }

        float d0 = 0.f, d1 = 0.f, d2 = 0.f, d3 = 0.f;
        #pragma unroll
        for (int k = 0; k < LF4; ++k) {
            float4 v = slab[k * TPB + tid];
            float4 w = w4[k];
            d0 = fmaf(v.x, w.x, d0); d1 = fmaf(v.y, w.y, d1);
            d2 = fmaf(v.z, w.z, d2); d3 = fmaf(v.w, w.w, d3);
        }
        #pragma unroll
        for (int k = 0; k < RF4; ++k) {
            float4 v = p[k];
            float4 w = w4[LF4 + k];
            d0 = fmaf(v.x, w.x, d0); d1 = fmaf(v.y, w.y, d1);
            d2 = fmaf(v.z, w.z, d2); d3 = fmaf(v.w, w.w, d3);
        }
        const float dot  = (d0 + d1) + (d2 + d3);
        const float diff = fmaxf(my_xn + lmn - 2.f * dot, 1e-10f);
        const float fac  = fmaxf(1.f + c * my_xn + c * lmn, 1e-6f);
        const float d    = sqrtf(diff) * sqrtf(fac);

        // fused witness: landmark POSITION s-1, ascending order, strict '<'
        if (d < b1v)      { b2v = b1v; b2i = b1i; b1v = d; b1i = s - 1; }
        else if (d < b2v) { b2v = d; b2i = s - 1; }

        if (s == L_) break;

        min_d = fminf(min_d, d);

        // wave argmax (tie -> lower n), carrying candidate's xn
        float v = min_d; int i = n; float x = my_xn;
        #pragma unroll
        for (int off = 32; off >= 1; off >>= 1) {
            float ov = __shfl_down(v, off);
            int   oi = __shfl_down(i, off);
            float ox = __shfl_down(x, off);
            if (ov > v || (ov == v && oi < i)) { v = ov; i = oi; x = ox; }
        }
        if ((tid & 63) == 0) {
            const int w = tid >> 6;
            wval[w] = v; widx[w] = i; wxn[w] = x;
        }
        __syncthreads();

        if (tid < 64) {   // wave 0: publish (parallel stores), hot-poll, reduce
            v = (tid < 8) ? wval[tid] : -__builtin_inff();
            i = (tid < 8) ? widx[tid] : 0x7FFFFFFF;
            x = (tid < 8) ? wxn[tid]  : 0.f;
            #pragma unroll
            for (int off = 4; off >= 1; off >>= 1) {
                float ov = __shfl_down(v, off);
                int   oi = __shfl_down(i, off);
                float ox = __shfl_down(x, off);
                if (ov > v || (ov == v && oi < i)) { v = ov; i = oi; x = ox; }
            }
            const size_t base = ((size_t)(b * 64 + s) * 32) * 2;   // u64 index
            if (tid == 0) {
                const unsigned long long key =
                    ((unsigned long long)__float_as_uint(v) << 32) |
                    (unsigned long long)(0xFFFFFFFFu - (unsigned)i);
                const unsigned long long enc64 =
                    (unsigned long long)(__float_as_uint(x) ^ 0x80000000u); // never 0
                // UNORDERED publish: both stores in flight simultaneously.
                __hip_atomic_store(&rec[base + wib * 2 + 0], key,
                                   __ATOMIC_RELAXED, __HIP_MEMORY_SCOPE_AGENT);
                __hip_atomic_store(&rec[base + wib * 2 + 1], enc64,
                                   __ATOMIC_RELAXED, __HIP_MEMORY_SCOPE_AGENT);
            }
            // hot poll: lane l -> record l (two adjacent u64s, parallel loads)
            unsigned long long myk, mye;
            for (;;) {
                myk = __hip_atomic_load(&rec[base + (tid & 31) * 2 + 0],
                                        __ATOMIC_RELAXED, __HIP_MEMORY_SCOPE_AGENT);
                mye = __hip_atomic_load(&rec[base + (tid & 31) * 2 + 1],
                                        __ATOMIC_RELAXED, __HIP_MEMORY_SCOPE_AGENT);
                if (__all((myk != 0ull) && (mye != 0ull))) break;
            }
            // max-reduce 32 distinct keys, carrying enc (lanes 32..63 duplicate)
            unsigned long long k = myk, e = mye;
            #pragma unroll
            for (int off = 32; off >= 1; off >>= 1) {
                unsigned long long ok = __shfl_down(k, off);
                unsigned long long oe = __shfl_down(e, off);
                if (ok > k) { k = ok; e = oe; }
            }
            if (tid == 0) {
                s_next = (int)(0xFFFFFFFFu - (unsigned)(k & 0xFFFFFFFFull));
                s_lmn  = __uint_as_float((unsigned)e ^ 0x80000000u);
            }
        }
        __syncthreads();
        lm    = s_next;
        lmn_c = s_lmn;
    }

    // emit my edge (top-2 landmark positions) into LDS bitmask
    {
        const int lo = min(b1i, b2i), hi = max(b1i, b2i);
        const int bitpos = lo * 64 + hi;
        atomicOr(&lmask[bitpos >> 5], 1u << (bitpos & 31));
    }
    __syncthreads();
    if (tid < 128) {
        unsigned w = lmask[tid];
        if (w) atomicOr(&gadj[b * 128 + tid], w);   // agent-scope RMW at LLC
    }
    __syncthreads();

    if (tid == 0) {
        __threadfence();
        unsigned prev = atomicAdd(&cnt[b], 1u);
        s_lead = (prev == 31u) ? 1 : 0;
    }
    __syncthreads();
    if (!s_lead) return;

    // ---- leader WG (last arriver): finalize this batch ----
    __threadfence();
    if (tid < 128) lmask[tid] = atomicOr(&gadj[b * 128 + tid], 0u);  // coherent read
    __syncthreads();

    unsigned long long m = 0ull;
    if (tid < 64) {
        m = ((unsigned long long)lmask[tid * 2 + 1] << 32) | lmask[tid * 2];
        for (int j = 0; j < 64; ++j)           // symmetrize: column bits
            if (lmask[j * 2 + (tid >> 5)] & (1u << (tid & 31))) m |= 1ull << j;
        labels[tid] = tid;
    }
    __syncthreads();

    for (int it = 0; it < 64; ++it) {          // synchronous min-label propagation
        int mn = 0;
        if (tid < 64) {
            mn = labels[tid];
            unsigned long long mm = m;
            while (mm) {
                int j = __ffsll(mm) - 1;
                int lj = labels[j];
                mn = mn < lj ? mn : lj;
                mm &= mm - 1;
            }
        }
        __syncthreads();
        if (tid < 64) labels[tid] = mn;
        __syncthreads();
    }

    if (tid < 64) {
        unsigned long long hi_mask = (tid < 63) ? (~0ull << (tid + 1)) : 0ull;
        int myedges = __popcll(m & hi_mask);
        int mycomp  = (labels[tid] == tid) ? 1 : 0;
        #pragma unroll
        for (int off = 32; off >= 1; off >>= 1) {
            myedges += __shfl_down(myedges, off);
            mycomp  += __shfl_down(mycomp, off);
        }
        if (tid == 0) {
            float beta0 = (float)mycomp;
            float beta1 = (float)(myedges - (64 - mycomp));
            out[b]      = beta0;
            out[8 + b]  = beta1;
            out[16 + b] = beta0 / 64.f;
            out[24 + b] = (beta1 > 3.f) ? 1.f : 0.f;
        }
    }
}

// ---------------------------------------------------------------------------
extern "C" void kernel_launch(void* const* d_in, const int* in_sizes, int n_in,
                              void* d_out, int out_size, void* d_ws, size_t ws_size,
                              hipStream_t stream)
{
    const float* emb = (const float*)d_in[0];
    const float* cs  = (const float*)d_in[1];
    float* out = (float*)d_out;

    char* ws = (char*)d_ws;
    unsigned long long* rec  = (unsigned long long*)(ws);
    unsigned int*       gadj = (unsigned int*)(ws + 262144);
    unsigned int*       cnt  = (unsigned int*)(ws + 266240);

    hipLaunchKernelGGL(init_kernel, dim3(66), dim3(1024), 0, stream,
                       (unsigned int*)ws);
    hipLaunchKernelGGL(fps_all_kernel, dim3(256), dim3(TPB), 0, stream,
                       emb, cs, rec, gadj, cnt, out);
}